// Round 5
// baseline (931.129 us; speedup 1.0000x reference)
//
#include <hip/hip_runtime.h>
#include <hip/hip_bf16.h>

#define B_   2
#define L_   2048
#define DIM_ 512
#define NH_  8
#define HD_  64
#define R_   8
#define EH_  16
#define T_   2

__device__ __forceinline__ float gelu_f(float x){
  return 0.5f * x * (1.0f + erff(x * 0.70710678118654752f));
}
__device__ __forceinline__ float softplus_f(float x){
  return (x > 20.f) ? x : log1pf(expf(x));
}

// ---------------------------------------------------------------------------
// k_misc: W2[h][n=k*8+r][d] (k<16: l2w, k==16: bias, k==17: zero pad),
//         eta, rope tables, init edge slot tables to -1.
// ---------------------------------------------------------------------------
__global__ __launch_bounds__(256) void k_misc(
    const float* __restrict__ l2w, const float* __restrict__ l2b,
    const float* __restrict__ step,
    float* __restrict__ W2, float* __restrict__ eta,
    float* __restrict__ ropeC, float* __restrict__ ropeS,
    int* __restrict__ esrc, int* __restrict__ edst)
{
  int idx = blockIdx.x * 256 + threadIdx.x;
  if (idx < NH_*144*64){
    int d = idx & 63;
    int n = (idx >> 6) % 144;
    int h = idx / (144*64);
    int k = n >> 3, r = n & 7;
    int col = h*512 + r*64 + d;
    float v = 0.f;
    if (k < 16) v = l2w[k*4096 + col];
    else if (k == 16) v = l2b[col];
    W2[idx] = v;
    return;
  }
  idx -= NH_*144*64;
  if (idx < T_*L_){ eta[idx] = softplus_f(step[idx]); return; }
  idx -= T_*L_;
  if (idx < 9*32){
    int d = idx & 31, rel = (idx >> 5) - 4;
    float invf = expf(-((float)d / 32.f) * 9.210340371976184f);  // ln(10000)
    float ang = (float)rel * invf;
    ropeC[idx] = cosf(ang); ropeS[idx] = sinf(ang);
    return;
  }
  idx -= 9*32;
  if (idx < 2*8*L_){
    if (idx < 8*L_) esrc[idx] = -1; else edst[idx - 8*L_] = -1;
    return;
  }
}

// ---------------------------------------------------------------------------
// k_gram: Gram[(h*8+r)][a][b] = sum_d W2[h][a*8+r][d] * W2[h][b*8+r][d]
// ---------------------------------------------------------------------------
__global__ __launch_bounds__(256) void k_gram(
    const float* __restrict__ W2, float* __restrict__ Gram)
{
  int idx = blockIdx.x * 256 + threadIdx.x;
  if (idx >= 8*8*17*17) return;
  int bq = idx % 17;
  int a  = (idx / 17) % 17;
  int r  = (idx / 289) & 7;
  int h  = idx / (289*8);
  const float* wa = W2 + ((size_t)(h*144 + a*8 + r))*64;
  const float* wb = W2 + ((size_t)(h*144 + bq*8 + r))*64;
  float s = 0.f;
  #pragma unroll 8
  for (int d = 0; d < 64; d++) s = fmaf(wa[d], wb[d], s);
  Gram[idx] = s;
}

// ---------------------------------------------------------------------------
// k_fill: scatter edge ids into per-node slot tables.
// ---------------------------------------------------------------------------
__global__ __launch_bounds__(256) void k_fill(
    const int* __restrict__ ei, const int* __restrict__ ej, int E,
    int* __restrict__ esrc, int* __restrict__ edst)
{
  int e = blockIdx.x * 256 + threadIdx.x;
  if (e >= E) return;
  int i = ei[e], j = ej[e];
  int o = j - i;                      // in [-4,4] \ {0}
  int slot = (o < 0) ? (o + 4) : (o + 3);
  esrc[slot*L_ + i] = e;
  edst[slot*L_ + j] = e;
}

// ---------------------------------------------------------------------------
// k_te: u[(b*512 + n)*2048 + l] = x[b,l,:] @ te_w[:,n] + te_b[n]   (d-major u)
// ---------------------------------------------------------------------------
__global__ __launch_bounds__(256) void k_te(
    const float* __restrict__ x, const float* __restrict__ w,
    const float* __restrict__ bias, float* __restrict__ u)
{
  __shared__ float As[16][64];
  __shared__ float Bs[16][64];
  const int m0 = blockIdx.x * 64;
  const int n0 = blockIdx.y * 64;
  const int tid = threadIdx.x;
  const int ty = tid >> 4, tx = tid & 15;
  float acc[4][4] = {};
  for (int k0 = 0; k0 < 512; k0 += 16){
    {
      int m = tid >> 2, seg = tid & 3;
      float4 v = *(const float4*)(x + (size_t)(m0 + m)*512 + k0 + seg*4);
      As[seg*4+0][m] = v.x; As[seg*4+1][m] = v.y;
      As[seg*4+2][m] = v.z; As[seg*4+3][m] = v.w;
    }
    {
      int k = tid >> 4, c = (tid & 15)*4;
      float4 v = *(const float4*)(w + (size_t)(k0 + k)*512 + n0 + c);
      *(float4*)&Bs[k][c] = v;
    }
    __syncthreads();
    #pragma unroll
    for (int k = 0; k < 16; k++){
      float4 a = *(const float4*)(&As[k][ty*4]);
      float4 b = *(const float4*)(&Bs[k][tx*4]);
      float av[4] = {a.x, a.y, a.z, a.w};
      float bv[4] = {b.x, b.y, b.z, b.w};
      #pragma unroll
      for (int ii = 0; ii < 4; ii++)
        #pragma unroll
        for (int jj = 0; jj < 4; jj++)
          acc[ii][jj] = fmaf(av[ii], bv[jj], acc[ii][jj]);
    }
    __syncthreads();
  }
  const int bb = m0 >> 11;
  const int lb = (m0 & 2047) + ty*4;
  #pragma unroll
  for (int jj = 0; jj < 4; jj++){
    int n = n0 + tx*4 + jj;
    float bv = bias[n];
    float4 o;
    o.x = acc[0][jj] + bv; o.y = acc[1][jj] + bv;
    o.z = acc[2][jj] + bv; o.w = acc[3][jj] + bv;
    *(float4*)&u[((size_t)(bb*512 + n))*2048 + lb] = o;
  }
}

// ---------------------------------------------------------------------------
// k_pq: node projections for both edge MLPs.
// ---------------------------------------------------------------------------
__global__ __launch_bounds__(256) void k_pq(
    const float* __restrict__ x, const float* __restrict__ a1w,
    const float* __restrict__ l1w, float* __restrict__ PQ)
{
  __shared__ float As[16][64];
  __shared__ float Bs[16][64];
  const int m0 = blockIdx.x * 64;
  const int tid = threadIdx.x;
  const int ty = tid >> 4, tx = tid & 15;
  const int c = (tid & 15) * 4;
  const int group = c >> 4;                 // 0..3
  const float* src = (group & 2) ? l1w : a1w;
  const int krow_off = (group & 1) ? 512 : 0;
  const int cc = c & 15;
  float acc[4][4] = {};
  for (int k0 = 0; k0 < 512; k0 += 16){
    {
      int m = tid >> 2, seg = tid & 3;
      float4 v = *(const float4*)(x + (size_t)(m0 + m)*512 + k0 + seg*4);
      As[seg*4+0][m] = v.x; As[seg*4+1][m] = v.y;
      As[seg*4+2][m] = v.z; As[seg*4+3][m] = v.w;
    }
    {
      int k = tid >> 4;
      float4 v = *(const float4*)(src + (size_t)(krow_off + k0 + k)*16 + cc);
      *(float4*)&Bs[k][c] = v;
    }
    __syncthreads();
    #pragma unroll
    for (int k = 0; k < 16; k++){
      float4 a = *(const float4*)(&As[k][ty*4]);
      float4 b = *(const float4*)(&Bs[k][tx*4]);
      float av[4] = {a.x, a.y, a.z, a.w};
      float bv[4] = {b.x, b.y, b.z, b.w};
      #pragma unroll
      for (int ii = 0; ii < 4; ii++)
        #pragma unroll
        for (int jj = 0; jj < 4; jj++)
          acc[ii][jj] = fmaf(av[ii], bv[jj], acc[ii][jj]);
    }
    __syncthreads();
  }
  #pragma unroll
  for (int ii = 0; ii < 4; ii++){
    int m = m0 + ty*4 + ii;
    float4 o;
    o.x = acc[ii][0]; o.y = acc[ii][1]; o.z = acc[ii][2]; o.w = acc[ii][3];
    *(float4*)&PQ[(size_t)m*64 + tx*4] = o;
  }
}

// ---------------------------------------------------------------------------
// k_feat2: alphas + h2 (k-major h2t AND e-major h2e).
// ---------------------------------------------------------------------------
__global__ __launch_bounds__(256) void k_feat2(
    const float* __restrict__ PQ, const int* __restrict__ ei, const int* __restrict__ ej,
    const float* __restrict__ a1b, const float* __restrict__ a2w,
    const float* __restrict__ a2b, const float* __restrict__ l1b,
    int E, float* __restrict__ alphas, float* __restrict__ h2t,
    float* __restrict__ h2e)
{
  int e = blockIdx.x * 256 + threadIdx.x;
  int b = blockIdx.y;
  if (e >= E) return;
  int i = ei[e], j = ej[e];
  const float* Pi = PQ + ((size_t)b*L_ + i)*64;
  const float* Pj = PQ + ((size_t)b*L_ + j)*64;
  float ha[16], hl[16];
  #pragma unroll
  for (int q = 0; q < 4; q++){
    float4 p1 = *(const float4*)(Pi + q*4);
    float4 q1 = *(const float4*)(Pj + 16 + q*4);
    float4 p2 = *(const float4*)(Pi + 32 + q*4);
    float4 q2 = *(const float4*)(Pj + 48 + q*4);
    ha[q*4+0] = p1.x + q1.x; ha[q*4+1] = p1.y + q1.y;
    ha[q*4+2] = p1.z + q1.z; ha[q*4+3] = p1.w + q1.w;
    hl[q*4+0] = p2.x + q2.x; hl[q*4+1] = p2.y + q2.y;
    hl[q*4+2] = p2.z + q2.z; hl[q*4+3] = p2.w + q2.w;
  }
  float av = a2b[0];
  #pragma unroll
  for (int n = 0; n < 16; n++){
    float g = gelu_f(ha[n] + a1b[n]);
    av += g * a2w[n];
  }
  alphas[(size_t)b*E + e] = softplus_f(av);
  float* he = h2e + ((size_t)b*E + e)*16;
  #pragma unroll
  for (int n = 0; n < 16; n++){
    float g = gelu_f(hl[n] + l1b[n]);
    h2t[((size_t)b*16 + n)*E + e] = g;
    he[n] = g;
  }
}

// ---------------------------------------------------------------------------
// k_S: per (b,h) x 64-edge tile:
//   diff[64e][64d] built from u + rope -> LDS
//   G[e][n] = diff @ W2^T  (GEMM, W2 in LDS, 4e x 9n per thread)
//   S[e][r] = sum_k m[k] G[e][k*8+r]  (LDS atomics)
//   t=0: ss[r] = m^T Gram_r m ; invn stored. coef = invn^2 * S -> global.
// ---------------------------------------------------------------------------
template<int TZERO>
__global__ __launch_bounds__(256) void k_S(
    const float* __restrict__ u, const float* __restrict__ W2,
    const float* __restrict__ Gram, const float* __restrict__ h2t,
    const float* __restrict__ ropeC, const float* __restrict__ ropeS,
    const int* __restrict__ ei, const int* __restrict__ ej,
    int E, float* __restrict__ invng, float* __restrict__ coefg)
{
  __shared__ float Wl[144][68];
  __shared__ float Dl[64][76];
  __shared__ float Hl[16][64];
  __shared__ float Sl[64][8];
  const int tid = threadIdx.x;
  const int e0 = blockIdx.x * 64;
  const int bh = blockIdx.y;
  const int b = bh >> 3, h = bh & 7;

  // load W2 slice (9216 floats, float4)
  {
    const float* Wg = W2 + (size_t)h*144*64;
    #pragma unroll
    for (int it = 0; it < 9; it++){
      int fi = it*256 + tid;            // 2304 float4's
      int n = fi >> 4, kk = (fi & 15)*4;
      float4 v = *(const float4*)(Wg + n*64 + kk);
      *(float4*)&Wl[n][kk] = v;
    }
  }
  // h2 tile (k-major)
  {
    int k = tid >> 4, es = (tid & 15)*4;
    #pragma unroll
    for (int q = 0; q < 4; q++){
      int ge = e0 + es + q;
      Hl[k][es+q] = (ge < E) ? h2t[((size_t)b*16 + k)*E + ge] : 0.f;
    }
  }
  // zero S
  ((float*)Sl)[tid] = 0.f;
  ((float*)Sl)[tid + 256] = 0.f;
  // diff build: lanes = edges, 4 dp-groups
  const int e = tid & 63;
  const int dpg = tid >> 6;
  const int ge = e0 + e;
  const bool val = (ge < E);
  const int ii = val ? ei[ge] : 0;
  const int jj = val ? ej[ge] : 0;
  const int ridx = ii - jj + 4;
  const float* ub = u + ((size_t)(b*512 + h*64))*2048;
  #pragma unroll
  for (int q = 0; q < 8; q++){
    int dp = dpg*8 + q;
    float c = ropeC[ridx*32 + dp], s = ropeS[ridx*32 + dp];
    float ui0 = ub[dp*2048 + ii],      ui1 = ub[(dp+32)*2048 + ii];
    float uj0 = ub[dp*2048 + jj],      uj1 = ub[(dp+32)*2048 + jj];
    Dl[e][dp]      = val ? (ui0*c - ui1*s - uj0) : 0.f;
    Dl[e][dp+32]   = val ? (ui1*c + ui0*s - uj1) : 0.f;
  }
  __syncthreads();

  // GEMM: G tile 4e x 9n per thread
  const int eg = tid >> 4, ng = tid & 15;
  const int ee = eg*4, nn = ng*9;
  float acc[4][9] = {};
  for (int kk = 0; kk < 64; kk += 4){
    float4 A[4];
    #pragma unroll
    for (int t = 0; t < 4; t++) A[t] = *(const float4*)&Dl[ee+t][kk];
    #pragma unroll
    for (int sx = 0; sx < 9; sx++){
      float4 bb = *(const float4*)&Wl[nn+sx][kk];
      #pragma unroll
      for (int t = 0; t < 4; t++){
        acc[t][sx] = fmaf(A[t].x, bb.x, acc[t][sx]);
        acc[t][sx] = fmaf(A[t].y, bb.y, acc[t][sx]);
        acc[t][sx] = fmaf(A[t].z, bb.z, acc[t][sx]);
        acc[t][sx] = fmaf(A[t].w, bb.w, acc[t][sx]);
      }
    }
  }
  // S-reduce
  #pragma unroll
  for (int sx = 0; sx < 9; sx++){
    int n = nn + sx;
    int k = n >> 3, r = n & 7;
    if (k > 16) continue;
    #pragma unroll
    for (int t = 0; t < 4; t++){
      float m = (k < 16) ? Hl[k][ee+t] : 1.f;
      atomicAdd(&Sl[ee+t][r], m*acc[t][sx]);
    }
  }
  __syncthreads();

  // finish: thread (rp = tid>>6, e = tid&63) -> 2 r's
  if (val){
    float m[17];
    #pragma unroll
    for (int k = 0; k < 16; k++) m[k] = Hl[k][e];
    m[16] = 1.f;
    const int rp = tid >> 6;
    #pragma unroll
    for (int rr = 0; rr < 2; rr++){
      int r = rp*2 + rr;
      float S = Sl[e][r];
      float iv;
      if (TZERO){
        const float* Gr = Gram + ((size_t)(h*8 + r))*289;
        float ss = 0.f;
        #pragma unroll
        for (int a = 0; a <= 16; a++){
          float inner = 0.f;
          #pragma unroll
          for (int bq = 0; bq <= 16; bq++)
            inner = fmaf(m[bq], Gr[a*17 + bq], inner);
          ss = fmaf(m[a], inner, ss);
        }
        iv = 1.f / fmaxf(sqrtf(ss), 1e-12f);
        invng[((size_t)bh*E + ge)*8 + r] = iv;
      } else {
        iv = invng[((size_t)bh*E + ge)*8 + r];
      }
      coefg[((size_t)bh*E + ge)*8 + r] = iv*iv*S;
    }
  }
}

// ---------------------------------------------------------------------------
// k_apply: per (b,h) x 64-node tile:
//   A[l][n] = sum_{src} m[k]*coef[r] - sum_{dst} m[k]*coef[r]
//   updW[l][d] = A @ W2  (GEMM)
//   + alpha*diff scatter terms recomputed pointwise, u_out = u_in - eta*upd.
// ---------------------------------------------------------------------------
__global__ __launch_bounds__(256) void k_apply(
    const float* __restrict__ uin, float* __restrict__ uout,
    const float* __restrict__ W2,
    const float* __restrict__ h2e, const float* __restrict__ coefg,
    const float* __restrict__ alphas,
    const float* __restrict__ ropeC, const float* __restrict__ ropeS,
    const int* __restrict__ esrc, const int* __restrict__ edst,
    const int* __restrict__ ei, const int* __restrict__ ej,
    const float* __restrict__ eta, int E, int t)
{
  __shared__ float Wl[144][68];
  __shared__ float Al[64][148];
  __shared__ float rC[288], rS[288];
  const int tid = threadIdx.x;
  const int l0 = blockIdx.x * 64;
  const int bh = blockIdx.y;
  const int b = bh >> 3, h = bh & 7;

  {
    const float* Wg = W2 + (size_t)h*144*64;
    #pragma unroll
    for (int it = 0; it < 9; it++){
      int fi = it*256 + tid;
      int n = fi >> 4, kk = (fi & 15)*4;
      float4 v = *(const float4*)(Wg + n*64 + kk);
      *(float4*)&Wl[n][kk] = v;
    }
  }
  for (int it = tid; it < 288; it += 256){ rC[it] = ropeC[it]; rS[it] = ropeS[it]; }
  for (int it = tid; it < 64*148; it += 256) ((float*)Al)[it] = 0.f;
  __syncthreads();

  // A-build: thread = (l = tid&63, nc = tid>>6) owns r-pair {nc*2, nc*2+1},
  // k index compile-time (no scratch).
  {
    const int l = tid & 63;
    const int nc = tid >> 6;
    const int r0 = nc*2;
    const int gl = l0 + l;
    float areg0[17], areg1[17];
    #pragma unroll
    for (int k = 0; k < 17; k++){ areg0[k] = 0.f; areg1[k] = 0.f; }
    for (int o = 0; o < 16; o++){
      int e = (o < 8) ? esrc[o*L_ + gl] : edst[(o-8)*L_ + gl];
      if (e < 0) continue;
      float sign = (o < 8) ? 1.f : -1.f;
      const float* hp = h2e + ((size_t)b*E + e)*16;
      const float* cp = coefg + ((size_t)bh*E + e)*8;
      float c0 = sign * cp[r0];
      float c1 = sign * cp[r0+1];
      float m[17];
      #pragma unroll
      for (int q = 0; q < 4; q++){
        float4 v = *(const float4*)(hp + q*4);
        m[q*4+0] = v.x; m[q*4+1] = v.y; m[q*4+2] = v.z; m[q*4+3] = v.w;
      }
      m[16] = 1.f;
      #pragma unroll
      for (int k = 0; k < 17; k++){
        areg0[k] = fmaf(m[k], c0, areg0[k]);
        areg1[k] = fmaf(m[k], c1, areg1[k]);
      }
    }
    #pragma unroll
    for (int k = 0; k < 17; k++){
      Al[l][k*8 + r0]     = areg0[k];
      Al[l][k*8 + r0 + 1] = areg1[k];
    }
  }
  __syncthreads();

  // GEMM: 4l x 4d per thread; lanes l-fast (lg = tid&15)
  const int lg = tid & 15, dg = tid >> 4;
  float acc[4][4] = {};
  for (int n = 0; n < 144; n += 4){
    float4 Av[4];
    #pragma unroll
    for (int tt = 0; tt < 4; tt++) Av[tt] = *(const float4*)&Al[lg*4+tt][n];
    #pragma unroll
    for (int q = 0; q < 4; q++){
      float4 bb = *(const float4*)&Wl[n+q][dg*4];
      #pragma unroll
      for (int tt = 0; tt < 4; tt++){
        float a = (q==0)?Av[tt].x:(q==1)?Av[tt].y:(q==2)?Av[tt].z:Av[tt].w;
        acc[tt][0] = fmaf(a, bb.x, acc[tt][0]);
        acc[tt][1] = fmaf(a, bb.y, acc[tt][1]);
        acc[tt][2] = fmaf(a, bb.z, acc[tt][2]);
        acc[tt][3] = fmaf(a, bb.w, acc[tt][3]);
      }
    }
  }

  // epilogue: alpha*diff terms + final update
  const float* ub = uin + ((size_t)(b*512 + h*64))*2048;
  float*       uo = uout + ((size_t)(b*512 + h*64))*2048;
  #pragma unroll
  for (int tt = 0; tt < 4; tt++){
    const int myl = l0 + lg*4 + tt;
    const float et = eta[t*L_ + myl];
    float ul[4], ulp[4], upd[4];
    #pragma unroll
    for (int q = 0; q < 4; q++){
      int d = dg*4 + q;
      int db = (d < 32) ? d + 32 : d - 32;
      ul[q]  = ub[d*2048 + myl];
      ulp[q] = ub[db*2048 + myl];
      upd[q] = acc[tt][q];
    }
    for (int o = 0; o < 8; o++){            // src edges (myl = i)
      int e = esrc[o*L_ + myl];
      if (e < 0) continue;
      int j = ej[e];
      float al = alphas[(size_t)b*E + e];
      int rix = (myl - j) + 4;
      #pragma unroll
      for (int q = 0; q < 4; q++){
        int d = dg*4 + q, p = d & 31;
        float c = rC[rix*32 + p], s = rS[rix*32 + p];
        float rope = (d < 32) ? (c*ul[q] - s*ulp[q]) : (c*ul[q] + s*ulp[q]);
        upd[q] = fmaf(al, rope - ub[d*2048 + j], upd[q]);
      }
    }
    for (int o = 0; o < 8; o++){            // dst edges (myl = j)
      int e = edst[o*L_ + myl];
      if (e < 0) continue;
      int i2 = ei[e];
      float al = alphas[(size_t)b*E + e];
      int rix = (i2 - myl) + 4;
      #pragma unroll
      for (int q = 0; q < 4; q++){
        int d = dg*4 + q, p = d & 31;
        int db = (d < 32) ? d + 32 : d - 32;
        float c = rC[rix*32 + p], s = rS[rix*32 + p];
        float uid  = ub[d*2048 + i2];
        float uidp = ub[db*2048 + i2];
        float rope = (d < 32) ? (c*uid - s*uidp) : (c*uid + s*uidp);
        upd[q] -= al * (rope - ul[q]);
      }
    }
    #pragma unroll
    for (int q = 0; q < 4; q++){
      int d = dg*4 + q;
      uo[d*2048 + myl] = ul[q] - et*upd[q];
    }
  }
}

// ---------------------------------------------------------------------------
// k_out: out[b,l,n] = u[b,:,l] @ out_w[:,n] + out_b[n], f32 store.
// ---------------------------------------------------------------------------
__global__ __launch_bounds__(256) void k_out(
    const float* __restrict__ u, const float* __restrict__ w,
    const float* __restrict__ bias, float* __restrict__ outp)
{
  __shared__ float As[16][64];
  __shared__ float Bs[16][64];
  const int m0 = blockIdx.x * 64;
  const int n0 = blockIdx.y * 64;
  const int tid = threadIdx.x;
  const int ty = tid >> 4, tx = tid & 15;
  const int bb = m0 >> 11;
  const int l0 = m0 & 2047;
  float acc[4][4] = {};
  for (int k0 = 0; k0 < 512; k0 += 16){
    {
      int k = tid >> 4, ls = (tid & 15)*4;
      float4 v = *(const float4*)&u[((size_t)(bb*512 + k0 + k))*2048 + l0 + ls];
      *(float4*)&As[k][ls] = v;
    }
    {
      int k = tid >> 4, c = (tid & 15)*4;
      float4 v = *(const float4*)(w + (size_t)(k0 + k)*512 + n0 + c);
      *(float4*)&Bs[k][c] = v;
    }
    __syncthreads();
    #pragma unroll
    for (int k = 0; k < 16; k++){
      float4 a = *(const float4*)(&As[k][ty*4]);
      float4 b = *(const float4*)(&Bs[k][tx*4]);
      float av[4] = {a.x, a.y, a.z, a.w};
      float bv[4] = {b.x, b.y, b.z, b.w};
      #pragma unroll
      for (int ii = 0; ii < 4; ii++)
        #pragma unroll
        for (int jj = 0; jj < 4; jj++)
          acc[ii][jj] = fmaf(av[ii], bv[jj], acc[ii][jj]);
    }
    __syncthreads();
  }
  float bv[4];
  #pragma unroll
  for (int jj = 0; jj < 4; jj++) bv[jj] = bias[n0 + tx*4 + jj];
  #pragma unroll
  for (int ii = 0; ii < 4; ii++){
    int l = l0 + ty*4 + ii;
    float4 o;
    o.x = acc[ii][0] + bv[0];
    o.y = acc[ii][1] + bv[1];
    o.z = acc[ii][2] + bv[2];
    o.w = acc[ii][3] + bv[3];
    *(float4*)&outp[((size_t)(bb*2048 + l))*512 + n0 + tx*4] = o;
  }
}

// ---------------------------------------------------------------------------
extern "C" void kernel_launch(void* const* d_in, const int* in_sizes, int n_in,
                              void* d_out, int out_size, void* d_ws, size_t ws_size,
                              hipStream_t stream)
{
  const float* x    = (const float*)d_in[0];
  const int*   ei   = (const int*)d_in[1];
  const int*   ej   = (const int*)d_in[2];
  const float* tew  = (const float*)d_in[3];
  const float* teb  = (const float*)d_in[4];
  const float* a1w  = (const float*)d_in[5];
  const float* a1b  = (const float*)d_in[6];
  const float* a2w  = (const float*)d_in[7];
  const float* a2b  = (const float*)d_in[8];
  const float* l1w  = (const float*)d_in[9];
  const float* l1b  = (const float*)d_in[10];
  const float* l2w  = (const float*)d_in[11];
  const float* l2b  = (const float*)d_in[12];
  const float* step = (const float*)d_in[13];
  const float* ow   = (const float*)d_in[14];
  const float* ob   = (const float*)d_in[15];
  float* outp = (float*)d_out;
  const int E = in_sizes[1];

  char* p = (char*)d_ws;
  auto carve = [&](size_t nbytes)->char*{
    char* q = p; p += (nbytes + 255) & ~(size_t)255; return q;
  };
  float* u0     = (float*)carve((size_t)B_*512*2048*4);
  float* u1     = (float*)carve((size_t)B_*512*2048*4);
  float* PQ     = (float*)carve((size_t)B_*L_*64*4);
  float* h2t    = (float*)carve((size_t)B_*16*E*4);
  float* h2e    = (float*)carve((size_t)B_*E*16*4);
  float* alphas = (float*)carve((size_t)B_*E*4);
  float* coefg  = (float*)carve((size_t)B_*NH_*E*8*4);
  float* invng  = (float*)carve((size_t)B_*NH_*E*8*4);
  float* W2     = (float*)carve((size_t)NH_*144*64*4);
  float* Gram   = (float*)carve((size_t)8*8*17*17*4);
  float* eta    = (float*)carve((size_t)T_*L_*4);
  float* ropeC  = (float*)carve((size_t)288*4);
  float* ropeS  = (float*)carve((size_t)288*4);
  int*   esrc   = (int*)carve((size_t)8*L_*4);
  int*   edst   = (int*)carve((size_t)8*L_*4);

  {
    int total = NH_*144*64 + T_*L_ + 9*32 + 2*8*L_;
    k_misc<<<dim3((total + 255)/256), dim3(256), 0, stream>>>(
        l2w, l2b, step, W2, eta, ropeC, ropeS, esrc, edst);
  }
  k_gram<<<dim3((8*8*17*17 + 255)/256), dim3(256), 0, stream>>>(W2, Gram);
  k_fill<<<dim3((E + 255)/256), dim3(256), 0, stream>>>(ei, ej, E, esrc, edst);
  k_te<<<dim3(64, 8), dim3(256), 0, stream>>>(x, tew, teb, u0);
  k_pq<<<dim3(64), dim3(256), 0, stream>>>(x, a1w, l1w, PQ);
  k_feat2<<<dim3((E + 255)/256, B_), dim3(256), 0, stream>>>(
      PQ, ei, ej, a1b, a2w, a2b, l1b, E, alphas, h2t, h2e);

  const int etiles = (E + 63)/64;
  float* ucur = u0;
  float* unxt = u1;
  for (int t = 0; t < T_; t++){
    if (t == 0)
      k_S<1><<<dim3(etiles, B_*NH_), dim3(256), 0, stream>>>(
          ucur, W2, Gram, h2t, ropeC, ropeS, ei, ej, E, invng, coefg);
    else
      k_S<0><<<dim3(etiles, B_*NH_), dim3(256), 0, stream>>>(
          ucur, W2, Gram, h2t, ropeC, ropeS, ei, ej, E, invng, coefg);
    k_apply<<<dim3(L_/64, B_*NH_), dim3(256), 0, stream>>>(
        ucur, unxt, W2, h2e, coefg, alphas, ropeC, ropeS,
        esrc, edst, ei, ej, eta, E, t);
    float* tmp = ucur; ucur = unxt; unxt = tmp;
  }

  k_out<<<dim3(64, 8), dim3(256), 0, stream>>>(ucur, ow, ob, outp);
}

// Round 6
// 818.881 us; speedup vs baseline: 1.1371x; 1.1371x over previous
//
#include <hip/hip_runtime.h>
#include <hip/hip_bf16.h>

#define B_   2
#define L_   2048
#define DIM_ 512
#define NH_  8
#define HD_  64
#define R_   8
#define EH_  16
#define T_   2

__device__ __forceinline__ float gelu_f(float x){
  return 0.5f * x * (1.0f + erff(x * 0.70710678118654752f));
}
__device__ __forceinline__ float softplus_f(float x){
  return (x > 20.f) ? x : log1pf(expf(x));
}

// ---------------------------------------------------------------------------
// k_misc: W2[h][n=k*8+r][d] (k<16: l2w, k==16: bias, k==17: zero pad),
//         eta, rope tables, init edge slot tables to -1.
// ---------------------------------------------------------------------------
__global__ __launch_bounds__(256) void k_misc(
    const float* __restrict__ l2w, const float* __restrict__ l2b,
    const float* __restrict__ step,
    float* __restrict__ W2, float* __restrict__ eta,
    float* __restrict__ ropeC, float* __restrict__ ropeS,
    int* __restrict__ esrc, int* __restrict__ edst)
{
  int idx = blockIdx.x * 256 + threadIdx.x;
  if (idx < NH_*144*64){
    int d = idx & 63;
    int n = (idx >> 6) % 144;
    int h = idx / (144*64);
    int k = n >> 3, r = n & 7;
    int col = h*512 + r*64 + d;
    float v = 0.f;
    if (k < 16) v = l2w[k*4096 + col];
    else if (k == 16) v = l2b[col];
    W2[idx] = v;
    return;
  }
  idx -= NH_*144*64;
  if (idx < T_*L_){ eta[idx] = softplus_f(step[idx]); return; }
  idx -= T_*L_;
  if (idx < 9*32){
    int d = idx & 31, rel = (idx >> 5) - 4;
    float invf = expf(-((float)d / 32.f) * 9.210340371976184f);  // ln(10000)
    float ang = (float)rel * invf;
    ropeC[idx] = cosf(ang); ropeS[idx] = sinf(ang);
    return;
  }
  idx -= 9*32;
  if (idx < 2*8*L_){
    if (idx < 8*L_) esrc[idx] = -1; else edst[idx - 8*L_] = -1;
    return;
  }
}

// ---------------------------------------------------------------------------
// k_gram: Gram[h][r][a][b] = sum_d W2[h][a*8+r][d] * W2[h][b*8+r][d]
// ---------------------------------------------------------------------------
__global__ __launch_bounds__(256) void k_gram(
    const float* __restrict__ W2, float* __restrict__ Gram)
{
  int idx = blockIdx.x * 256 + threadIdx.x;
  if (idx >= 8*8*17*17) return;
  int bq = idx % 17;
  int a  = (idx / 17) % 17;
  int r  = (idx / 289) & 7;
  int h  = idx / (289*8);
  const float* wa = W2 + ((size_t)(h*144 + a*8 + r))*64;
  const float* wb = W2 + ((size_t)(h*144 + bq*8 + r))*64;
  float s = 0.f;
  #pragma unroll 8
  for (int d = 0; d < 64; d++) s = fmaf(wa[d], wb[d], s);
  Gram[idx] = s;
}

// ---------------------------------------------------------------------------
// k_fill: scatter edge ids into per-node slot tables.
// ---------------------------------------------------------------------------
__global__ __launch_bounds__(256) void k_fill(
    const int* __restrict__ ei, const int* __restrict__ ej, int E,
    int* __restrict__ esrc, int* __restrict__ edst)
{
  int e = blockIdx.x * 256 + threadIdx.x;
  if (e >= E) return;
  int i = ei[e], j = ej[e];
  int o = j - i;                      // in [-4,4] \ {0}
  int slot = (o < 0) ? (o + 4) : (o + 3);
  esrc[slot*L_ + i] = e;
  edst[slot*L_ + j] = e;
}

// ---------------------------------------------------------------------------
// k_te: u[(b*512 + n)*2048 + l] = x[b,l,:] @ te_w[:,n] + te_b[n]   (d-major u)
// ---------------------------------------------------------------------------
__global__ __launch_bounds__(256) void k_te(
    const float* __restrict__ x, const float* __restrict__ w,
    const float* __restrict__ bias, float* __restrict__ u)
{
  __shared__ float As[16][64];
  __shared__ float Bs[16][64];
  const int m0 = blockIdx.x * 64;
  const int n0 = blockIdx.y * 64;
  const int tid = threadIdx.x;
  const int ty = tid >> 4, tx = tid & 15;
  float acc[4][4] = {};
  for (int k0 = 0; k0 < 512; k0 += 16){
    {
      int m = tid >> 2, seg = tid & 3;
      float4 v = *(const float4*)(x + (size_t)(m0 + m)*512 + k0 + seg*4);
      As[seg*4+0][m] = v.x; As[seg*4+1][m] = v.y;
      As[seg*4+2][m] = v.z; As[seg*4+3][m] = v.w;
    }
    {
      int k = tid >> 4, c = (tid & 15)*4;
      float4 v = *(const float4*)(w + (size_t)(k0 + k)*512 + n0 + c);
      *(float4*)&Bs[k][c] = v;
    }
    __syncthreads();
    #pragma unroll
    for (int k = 0; k < 16; k++){
      float4 a = *(const float4*)(&As[k][ty*4]);
      float4 b = *(const float4*)(&Bs[k][tx*4]);
      float av[4] = {a.x, a.y, a.z, a.w};
      float bv[4] = {b.x, b.y, b.z, b.w};
      #pragma unroll
      for (int ii = 0; ii < 4; ii++)
        #pragma unroll
        for (int jj = 0; jj < 4; jj++)
          acc[ii][jj] = fmaf(av[ii], bv[jj], acc[ii][jj]);
    }
    __syncthreads();
  }
  const int bb = m0 >> 11;
  const int lb = (m0 & 2047) + ty*4;
  #pragma unroll
  for (int jj = 0; jj < 4; jj++){
    int n = n0 + tx*4 + jj;
    float bv = bias[n];
    float4 o;
    o.x = acc[0][jj] + bv; o.y = acc[1][jj] + bv;
    o.z = acc[2][jj] + bv; o.w = acc[3][jj] + bv;
    *(float4*)&u[((size_t)(bb*512 + n))*2048 + lb] = o;
  }
}

// ---------------------------------------------------------------------------
// k_pq: node projections for both edge MLPs.
// ---------------------------------------------------------------------------
__global__ __launch_bounds__(256) void k_pq(
    const float* __restrict__ x, const float* __restrict__ a1w,
    const float* __restrict__ l1w, float* __restrict__ PQ)
{
  __shared__ float As[16][64];
  __shared__ float Bs[16][64];
  const int m0 = blockIdx.x * 64;
  const int tid = threadIdx.x;
  const int ty = tid >> 4, tx = tid & 15;
  const int c = (tid & 15) * 4;
  const int group = c >> 4;                 // 0..3
  const float* src = (group & 2) ? l1w : a1w;
  const int krow_off = (group & 1) ? 512 : 0;
  const int cc = c & 15;
  float acc[4][4] = {};
  for (int k0 = 0; k0 < 512; k0 += 16){
    {
      int m = tid >> 2, seg = tid & 3;
      float4 v = *(const float4*)(x + (size_t)(m0 + m)*512 + k0 + seg*4);
      As[seg*4+0][m] = v.x; As[seg*4+1][m] = v.y;
      As[seg*4+2][m] = v.z; As[seg*4+3][m] = v.w;
    }
    {
      int k = tid >> 4;
      float4 v = *(const float4*)(src + (size_t)(krow_off + k0 + k)*16 + cc);
      *(float4*)&Bs[k][c] = v;
    }
    __syncthreads();
    #pragma unroll
    for (int k = 0; k < 16; k++){
      float4 a = *(const float4*)(&As[k][ty*4]);
      float4 b = *(const float4*)(&Bs[k][tx*4]);
      float av[4] = {a.x, a.y, a.z, a.w};
      float bv[4] = {b.x, b.y, b.z, b.w};
      #pragma unroll
      for (int ii = 0; ii < 4; ii++)
        #pragma unroll
        for (int jj = 0; jj < 4; jj++)
          acc[ii][jj] = fmaf(av[ii], bv[jj], acc[ii][jj]);
    }
    __syncthreads();
  }
  #pragma unroll
  for (int ii = 0; ii < 4; ii++){
    int m = m0 + ty*4 + ii;
    float4 o;
    o.x = acc[ii][0]; o.y = acc[ii][1]; o.z = acc[ii][2]; o.w = acc[ii][3];
    *(float4*)&PQ[(size_t)m*64 + tx*4] = o;
  }
}

// ---------------------------------------------------------------------------
// k_feat2: alphas + h2e (e-major).
// ---------------------------------------------------------------------------
__global__ __launch_bounds__(256) void k_feat2(
    const float* __restrict__ PQ, const int* __restrict__ ei, const int* __restrict__ ej,
    const float* __restrict__ a1b, const float* __restrict__ a2w,
    const float* __restrict__ a2b, const float* __restrict__ l1b,
    int E, float* __restrict__ alphas, float* __restrict__ h2e)
{
  int e = blockIdx.x * 256 + threadIdx.x;
  int b = blockIdx.y;
  if (e >= E) return;
  int i = ei[e], j = ej[e];
  const float* Pi = PQ + ((size_t)b*L_ + i)*64;
  const float* Pj = PQ + ((size_t)b*L_ + j)*64;
  float ha[16], hl[16];
  #pragma unroll
  for (int q = 0; q < 4; q++){
    float4 p1 = *(const float4*)(Pi + q*4);
    float4 q1 = *(const float4*)(Pj + 16 + q*4);
    float4 p2 = *(const float4*)(Pi + 32 + q*4);
    float4 q2 = *(const float4*)(Pj + 48 + q*4);
    ha[q*4+0] = p1.x + q1.x; ha[q*4+1] = p1.y + q1.y;
    ha[q*4+2] = p1.z + q1.z; ha[q*4+3] = p1.w + q1.w;
    hl[q*4+0] = p2.x + q2.x; hl[q*4+1] = p2.y + q2.y;
    hl[q*4+2] = p2.z + q2.z; hl[q*4+3] = p2.w + q2.w;
  }
  float av = a2b[0];
  #pragma unroll
  for (int n = 0; n < 16; n++){
    float g = gelu_f(ha[n] + a1b[n]);
    av += g * a2w[n];
  }
  alphas[(size_t)b*E + e] = softplus_f(av);
  float* he = h2e + ((size_t)b*E + e)*16;
  #pragma unroll
  for (int n = 0; n < 16; n++){
    float g = gelu_f(hl[n] + l1b[n]);
    he[n] = g;
  }
}

// ---------------------------------------------------------------------------
// k_S (register formulation): lane = edge, diff[64] in VGPRs, W broadcast
// from LDS (wave-uniform -> conflict-free), S[8] in regs, no atomics.
//   S[e][r] = sum_k m[k] * (diff[e] . W2[h][k*8+r])
//   TZERO: ss[r] = m17^T Gram_r m17 (LDS, uniform), invn stored.
//   coef[e][r] = invn^2 * S.
// ---------------------------------------------------------------------------
template<int TZERO>
__global__ __launch_bounds__(256) void k_S(
    const float* __restrict__ u, const float* __restrict__ W2,
    const float* __restrict__ Gram, const float* __restrict__ h2e,
    const float* __restrict__ ropeC, const float* __restrict__ ropeS,
    const int* __restrict__ ei, const int* __restrict__ ej,
    int E, float* __restrict__ invng, float* __restrict__ coefg)
{
  __shared__ float Wl[136*68];     // row stride 68 floats (16B-aligned rows)
  __shared__ float Gl[8*289];
  __shared__ float rCT[32*12];     // [p][rel] so lanes' rel spread banks
  __shared__ float rST[32*12];
  const int tid = threadIdx.x;
  const int bh = blockIdx.y;
  const int b = bh >> 3, h = bh & 7;

  {
    const float* Wg = W2 + (size_t)h*144*64;
    for (int fi = tid; fi < 2176; fi += 256){
      int n = fi >> 4, kq = (fi & 15)*4;
      *(float4*)&Wl[n*68 + kq] = *(const float4*)(Wg + n*64 + kq);
    }
  }
  if (TZERO){
    for (int it = tid; it < 2312; it += 256) Gl[it] = Gram[(size_t)h*2312 + it];
  }
  for (int it = tid; it < 288; it += 256){
    int rix = it >> 5, p = it & 31;
    rCT[p*12 + rix] = ropeC[it];
    rST[p*12 + rix] = ropeS[it];
  }
  __syncthreads();

  const int ge = blockIdx.x*256 + tid;
  const bool val = (ge < E);
  const int gi = val ? ge : 0;
  const int ii = ei[gi], jj = ej[gi];
  const int rix = ii - jj + 4;
  const float* ub = u + ((size_t)(b*512 + h*64))*2048;

  float m[16];
  {
    const float* hp = h2e + ((size_t)b*E + gi)*16;
    #pragma unroll
    for (int q = 0; q < 4; q++){
      float4 v = *(const float4*)(hp + q*4);
      m[q*4+0] = v.x; m[q*4+1] = v.y; m[q*4+2] = v.z; m[q*4+3] = v.w;
    }
  }

  float diffv[64];
  #pragma unroll
  for (int dp = 0; dp < 32; dp++){
    float c = rCT[dp*12 + rix], s = rST[dp*12 + rix];
    float ui0 = ub[dp*2048 + ii], ui1 = ub[(dp+32)*2048 + ii];
    float uj0 = ub[dp*2048 + jj], uj1 = ub[(dp+32)*2048 + jj];
    diffv[dp]    = ui0*c - ui1*s - uj0;
    diffv[dp+32] = ui1*c + ui0*s - uj1;
  }

  float S[8] = {};
  #pragma unroll
  for (int k = 0; k < 17; k++){
    float mk = (k < 16) ? m[k] : 1.f;
    #pragma unroll
    for (int r = 0; r < 8; r++){
      const float* wr = &Wl[(k*8+r)*68];
      float g = 0.f;
      #pragma unroll
      for (int dq = 0; dq < 16; dq++){
        float4 w = *(const float4*)(wr + dq*4);
        g = fmaf(diffv[dq*4+0], w.x, g);
        g = fmaf(diffv[dq*4+1], w.y, g);
        g = fmaf(diffv[dq*4+2], w.z, g);
        g = fmaf(diffv[dq*4+3], w.w, g);
      }
      S[r] = fmaf(mk, g, S[r]);
    }
  }

  if (val){
    float* cg = coefg + ((size_t)bh*E + ge)*8;
    if (TZERO){
      float m17[17];
      #pragma unroll
      for (int k = 0; k < 16; k++) m17[k] = m[k];
      m17[16] = 1.f;
      float* ig = invng + ((size_t)bh*E + ge)*8;
      #pragma unroll
      for (int r = 0; r < 8; r++){
        float ss = 0.f;
        #pragma unroll
        for (int a = 0; a < 17; a++){
          float inner = 0.f;
          #pragma unroll
          for (int bq = 0; bq < 17; bq++)
            inner = fmaf(m17[bq], Gl[r*289 + a*17 + bq], inner);
          ss = fmaf(m17[a], inner, ss);
        }
        float iv = 1.f / fmaxf(sqrtf(ss), 1e-12f);
        ig[r] = iv;
        cg[r] = iv*iv*S[r];
      }
    } else {
      const float* ig = invng + ((size_t)bh*E + ge)*8;
      #pragma unroll
      for (int r = 0; r < 8; r++){
        float iv = ig[r];
        cg[r] = iv*iv*S[r];
      }
    }
  }
}

// ---------------------------------------------------------------------------
// k_apply: per (b,h) x 64-node tile:
//   A[l][n] = sum_{src} m[k]*coef[r] - sum_{dst} m[k]*coef[r]
//   updW[l][d] = A @ W2  (GEMM)
//   + alpha*diff scatter terms recomputed pointwise, u_out = u_in - eta*upd.
// ---------------------------------------------------------------------------
__global__ __launch_bounds__(256) void k_apply(
    const float* __restrict__ uin, float* __restrict__ uout,
    const float* __restrict__ W2,
    const float* __restrict__ h2e, const float* __restrict__ coefg,
    const float* __restrict__ alphas,
    const float* __restrict__ ropeC, const float* __restrict__ ropeS,
    const int* __restrict__ esrc, const int* __restrict__ edst,
    const int* __restrict__ ei, const int* __restrict__ ej,
    const float* __restrict__ eta, int E, int t)
{
  __shared__ float Wl[144][68];
  __shared__ float Al[64][148];
  __shared__ float rC[288], rS[288];
  const int tid = threadIdx.x;
  const int l0 = blockIdx.x * 64;
  const int bh = blockIdx.y;
  const int b = bh >> 3, h = bh & 7;

  {
    const float* Wg = W2 + (size_t)h*144*64;
    #pragma unroll
    for (int it = 0; it < 9; it++){
      int fi = it*256 + tid;
      int n = fi >> 4, kk = (fi & 15)*4;
      float4 v = *(const float4*)(Wg + n*64 + kk);
      *(float4*)&Wl[n][kk] = v;
    }
  }
  for (int it = tid; it < 288; it += 256){ rC[it] = ropeC[it]; rS[it] = ropeS[it]; }
  for (int it = tid; it < 64*148; it += 256) ((float*)Al)[it] = 0.f;
  __syncthreads();

  // A-build: thread = (l = tid&63, nc = tid>>6) owns r-pair {nc*2, nc*2+1}.
  {
    const int l = tid & 63;
    const int nc = tid >> 6;
    const int r0 = nc*2;
    const int gl = l0 + l;
    float areg0[17], areg1[17];
    #pragma unroll
    for (int k = 0; k < 17; k++){ areg0[k] = 0.f; areg1[k] = 0.f; }
    for (int o = 0; o < 16; o++){
      int e = (o < 8) ? esrc[o*L_ + gl] : edst[(o-8)*L_ + gl];
      if (e < 0) continue;
      float sign = (o < 8) ? 1.f : -1.f;
      const float* hp = h2e + ((size_t)b*E + e)*16;
      const float* cp = coefg + ((size_t)bh*E + e)*8;
      float c0 = sign * cp[r0];
      float c1 = sign * cp[r0+1];
      float m[17];
      #pragma unroll
      for (int q = 0; q < 4; q++){
        float4 v = *(const float4*)(hp + q*4);
        m[q*4+0] = v.x; m[q*4+1] = v.y; m[q*4+2] = v.z; m[q*4+3] = v.w;
      }
      m[16] = 1.f;
      #pragma unroll
      for (int k = 0; k < 17; k++){
        areg0[k] = fmaf(m[k], c0, areg0[k]);
        areg1[k] = fmaf(m[k], c1, areg1[k]);
      }
    }
    #pragma unroll
    for (int k = 0; k < 17; k++){
      Al[l][k*8 + r0]     = areg0[k];
      Al[l][k*8 + r0 + 1] = areg1[k];
    }
  }
  __syncthreads();

  // GEMM: 4l x 4d per thread; lanes l-fast (lg = tid&15)
  const int lg = tid & 15, dg = tid >> 4;
  float acc[4][4] = {};
  for (int n = 0; n < 144; n += 4){
    float4 Av[4];
    #pragma unroll
    for (int tt = 0; tt < 4; tt++) Av[tt] = *(const float4*)&Al[lg*4+tt][n];
    #pragma unroll
    for (int q = 0; q < 4; q++){
      float4 bb = *(const float4*)&Wl[n+q][dg*4];
      #pragma unroll
      for (int tt = 0; tt < 4; tt++){
        float a = (q==0)?Av[tt].x:(q==1)?Av[tt].y:(q==2)?Av[tt].z:Av[tt].w;
        acc[tt][0] = fmaf(a, bb.x, acc[tt][0]);
        acc[tt][1] = fmaf(a, bb.y, acc[tt][1]);
        acc[tt][2] = fmaf(a, bb.z, acc[tt][2]);
        acc[tt][3] = fmaf(a, bb.w, acc[tt][3]);
      }
    }
  }

  // epilogue: alpha*diff terms + final update
  const float* ub = uin + ((size_t)(b*512 + h*64))*2048;
  float*       uo = uout + ((size_t)(b*512 + h*64))*2048;
  #pragma unroll
  for (int tt = 0; tt < 4; tt++){
    const int myl = l0 + lg*4 + tt;
    const float et = eta[t*L_ + myl];
    float ul[4], ulp[4], upd[4];
    #pragma unroll
    for (int q = 0; q < 4; q++){
      int d = dg*4 + q;
      int db = (d < 32) ? d + 32 : d - 32;
      ul[q]  = ub[d*2048 + myl];
      ulp[q] = ub[db*2048 + myl];
      upd[q] = acc[tt][q];
    }
    for (int o = 0; o < 8; o++){            // src edges (myl = i)
      int e = esrc[o*L_ + myl];
      if (e < 0) continue;
      int j = ej[e];
      float al = alphas[(size_t)b*E + e];
      int rix = (myl - j) + 4;
      #pragma unroll
      for (int q = 0; q < 4; q++){
        int d = dg*4 + q, p = d & 31;
        float c = rC[rix*32 + p], s = rS[rix*32 + p];
        float rope = (d < 32) ? (c*ul[q] - s*ulp[q]) : (c*ul[q] + s*ulp[q]);
        upd[q] = fmaf(al, rope - ub[d*2048 + j], upd[q]);
      }
    }
    for (int o = 0; o < 8; o++){            // dst edges (myl = j)
      int e = edst[o*L_ + myl];
      if (e < 0) continue;
      int i2 = ei[e];
      float al = alphas[(size_t)b*E + e];
      int rix = (i2 - myl) + 4;
      #pragma unroll
      for (int q = 0; q < 4; q++){
        int d = dg*4 + q, p = d & 31;
        int db = (d < 32) ? d + 32 : d - 32;
        float c = rC[rix*32 + p], s = rS[rix*32 + p];
        float uid  = ub[d*2048 + i2];
        float uidp = ub[db*2048 + i2];
        float rope = (d < 32) ? (c*uid - s*uidp) : (c*uid + s*uidp);
        upd[q] -= al * (rope - ul[q]);
      }
    }
    #pragma unroll
    for (int q = 0; q < 4; q++){
      int d = dg*4 + q;
      uo[d*2048 + myl] = ul[q] - et*upd[q];
    }
  }
}

// ---------------------------------------------------------------------------
// k_out: out[b,l,n] = u[b,:,l] @ out_w[:,n] + out_b[n], f32 store.
// ---------------------------------------------------------------------------
__global__ __launch_bounds__(256) void k_out(
    const float* __restrict__ u, const float* __restrict__ w,
    const float* __restrict__ bias, float* __restrict__ outp)
{
  __shared__ float As[16][64];
  __shared__ float Bs[16][64];
  const int m0 = blockIdx.x * 64;
  const int n0 = blockIdx.y * 64;
  const int tid = threadIdx.x;
  const int ty = tid >> 4, tx = tid & 15;
  const int bb = m0 >> 11;
  const int l0 = m0 & 2047;
  float acc[4][4] = {};
  for (int k0 = 0; k0 < 512; k0 += 16){
    {
      int k = tid >> 4, ls = (tid & 15)*4;
      float4 v = *(const float4*)&u[((size_t)(bb*512 + k0 + k))*2048 + l0 + ls];
      *(float4*)&As[k][ls] = v;
    }
    {
      int k = tid >> 4, c = (tid & 15)*4;
      float4 v = *(const float4*)(w + (size_t)(k0 + k)*512 + n0 + c);
      *(float4*)&Bs[k][c] = v;
    }
    __syncthreads();
    #pragma unroll
    for (int k = 0; k < 16; k++){
      float4 a = *(const float4*)(&As[k][ty*4]);
      float4 b = *(const float4*)(&Bs[k][tx*4]);
      float av[4] = {a.x, a.y, a.z, a.w};
      float bv[4] = {b.x, b.y, b.z, b.w};
      #pragma unroll
      for (int ii = 0; ii < 4; ii++)
        #pragma unroll
        for (int jj = 0; jj < 4; jj++)
          acc[ii][jj] = fmaf(av[ii], bv[jj], acc[ii][jj]);
    }
    __syncthreads();
  }
  float bv[4];
  #pragma unroll
  for (int jj = 0; jj < 4; jj++) bv[jj] = bias[n0 + tx*4 + jj];
  #pragma unroll
  for (int ii = 0; ii < 4; ii++){
    int l = l0 + ty*4 + ii;
    float4 o;
    o.x = acc[ii][0] + bv[0];
    o.y = acc[ii][1] + bv[1];
    o.z = acc[ii][2] + bv[2];
    o.w = acc[ii][3] + bv[3];
    *(float4*)&outp[((size_t)(bb*2048 + l))*512 + n0 + tx*4] = o;
  }
}

// ---------------------------------------------------------------------------
extern "C" void kernel_launch(void* const* d_in, const int* in_sizes, int n_in,
                              void* d_out, int out_size, void* d_ws, size_t ws_size,
                              hipStream_t stream)
{
  const float* x    = (const float*)d_in[0];
  const int*   ei   = (const int*)d_in[1];
  const int*   ej   = (const int*)d_in[2];
  const float* tew  = (const float*)d_in[3];
  const float* teb  = (const float*)d_in[4];
  const float* a1w  = (const float*)d_in[5];
  const float* a1b  = (const float*)d_in[6];
  const float* a2w  = (const float*)d_in[7];
  const float* a2b  = (const float*)d_in[8];
  const float* l1w  = (const float*)d_in[9];
  const float* l1b  = (const float*)d_in[10];
  const float* l2w  = (const float*)d_in[11];
  const float* l2b  = (const float*)d_in[12];
  const float* step = (const float*)d_in[13];
  const float* ow   = (const float*)d_in[14];
  const float* ob   = (const float*)d_in[15];
  float* outp = (float*)d_out;
  const int E = in_sizes[1];

  char* p = (char*)d_ws;
  auto carve = [&](size_t nbytes)->char*{
    char* q = p; p += (nbytes + 255) & ~(size_t)255; return q;
  };
  float* u0     = (float*)carve((size_t)B_*512*2048*4);
  float* u1     = (float*)carve((size_t)B_*512*2048*4);
  float* PQ     = (float*)carve((size_t)B_*L_*64*4);
  float* h2e    = (float*)carve((size_t)B_*E*16*4);
  float* alphas = (float*)carve((size_t)B_*E*4);
  float* coefg  = (float*)carve((size_t)B_*NH_*E*8*4);
  float* invng  = (float*)carve((size_t)B_*NH_*E*8*4);
  float* W2     = (float*)carve((size_t)NH_*144*64*4);
  float* Gram   = (float*)carve((size_t)8*8*17*17*4);
  float* eta    = (float*)carve((size_t)T_*L_*4);
  float* ropeC  = (float*)carve((size_t)288*4);
  float* ropeS  = (float*)carve((size_t)288*4);
  int*   esrc   = (int*)carve((size_t)8*L_*4);
  int*   edst   = (int*)carve((size_t)8*L_*4);

  {
    int total = NH_*144*64 + T_*L_ + 9*32 + 2*8*L_;
    k_misc<<<dim3((total + 255)/256), dim3(256), 0, stream>>>(
        l2w, l2b, step, W2, eta, ropeC, ropeS, esrc, edst);
  }
  k_gram<<<dim3((8*8*17*17 + 255)/256), dim3(256), 0, stream>>>(W2, Gram);
  k_fill<<<dim3((E + 255)/256), dim3(256), 0, stream>>>(ei, ej, E, esrc, edst);
  k_te<<<dim3(64, 8), dim3(256), 0, stream>>>(x, tew, teb, u0);
  k_pq<<<dim3(64), dim3(256), 0, stream>>>(x, a1w, l1w, PQ);
  k_feat2<<<dim3((E + 255)/256, B_), dim3(256), 0, stream>>>(
      PQ, ei, ej, a1b, a2w, a2b, l1b, E, alphas, h2e);

  const int etiles = (E + 255)/256;
  float* ucur = u0;
  float* unxt = u1;
  for (int t = 0; t < T_; t++){
    if (t == 0)
      k_S<1><<<dim3(etiles, B_*NH_), dim3(256), 0, stream>>>(
          ucur, W2, Gram, h2e, ropeC, ropeS, ei, ej, E, invng, coefg);
    else
      k_S<0><<<dim3(etiles, B_*NH_), dim3(256), 0, stream>>>(
          ucur, W2, Gram, h2e, ropeC, ropeS, ei, ej, E, invng, coefg);
    k_apply<<<dim3(L_/64, B_*NH_), dim3(256), 0, stream>>>(
        ucur, unxt, W2, h2e, coefg, alphas, ropeC, ropeS,
        esrc, edst, ei, ej, eta, E, t);
    float* tmp = ucur; ucur = unxt; unxt = tmp;
  }

  k_out<<<dim3(64, 8), dim3(256), 0, stream>>>(ucur, ow, ob, outp);
}